// Round 9
// baseline (355.271 us; speedup 1.0000x reference)
//
#include <hip/hip_runtime.h>
#include <hip/hip_bf16.h>
#include <hip/hip_cooperative_groups.h>
#include <math.h>

#define NB 8
#define SQ 2048
#define NSP 8    // kv splits in flash phase

typedef __attribute__((ext_vector_type(8))) short short8;
typedef __attribute__((ext_vector_type(4))) float f32x4;

__device__ __forceinline__ short f2bf(float f) {
    union { float f; unsigned u; } v; v.f = f;
    unsigned r = v.u + 0x7FFF + ((v.u >> 16) & 1);  // RNE
    return (short)(r >> 16);
}
__device__ __forceinline__ float bf2f(short s) {
    union { unsigned u; float f; } v; v.u = ((unsigned)(unsigned short)s) << 16;
    return v.f;
}

// ================= cooperative mega-kernel (phases == fallback kernels) ==========
__global__ __launch_bounds__(256, 4) void k_mega(
    const float* __restrict__ obs, const float* __restrict__ Wq,
    const float* __restrict__ Wk,  const float* __restrict__ Wv,
    const float* __restrict__ W1,  const float* __restrict__ b1,
    const float* __restrict__ W2,  const float* __restrict__ b2,
    float* __restrict__ x, float* __restrict__ attn,
    short* __restrict__ wt, short* __restrict__ qw, short* __restrict__ kw,
    short* __restrict__ vt, float* __restrict__ lpart, float* __restrict__ linv,
    short* __restrict__ pbuf, float* __restrict__ op)
{
    namespace cg = cooperative_groups;
    cg::grid_group grid = cg::this_grid();
    __shared__ __align__(16) char smem[18688];
    const int bid = threadIdx.y * 0 + blockIdx.x;
    const int tid = threadIdx.x, w = tid >> 6, l = tid & 63, lg = l >> 4, lc = l & 15;
    const int gsz = gridDim.x;
    short8 ones;
    #pragma unroll
    for (int i = 0; i < 8; ++i) ones[i] = (short)0x3F80;   // bf16 1.0

    // ---------- P0: build WT bf16 [192][256]
    for (int o = bid * 256 + tid; o < 192 * 256; o += gsz * 256) {
        int row = o >> 8, e = o & 255;
        int wsel = row >> 6, d = row & 63;
        const float* W = (wsel == 0) ? Wq : ((wsel == 1) ? Wk : Wv);
        wt[o] = f2bf(W[e * 64 + d]);
    }
    grid.sync();

    // ---------- P1: projection, 16 rows per tile, grid-stride over 1024 tiles
    {
        short (*ldsv)[18] = (short(*)[18])smem;
        for (int tb = bid; tb < 1024; tb += gsz) {
            int r0 = tb * 16;
            int arow = r0 + lc;
            f32x4 accq = {0.f,0.f,0.f,0.f}, acck = {0.f,0.f,0.f,0.f}, accv = {0.f,0.f,0.f,0.f};
            const short* wqp = wt + (size_t)(w * 16 + lc) * 256;
            const short* wkp = wt + (size_t)(64 + w * 16 + lc) * 256;
            const short* wvp = wt + (size_t)(128 + w * 16 + lc) * 256;
            #pragma unroll
            for (int ks = 0; ks < 8; ++ks) {
                int e0 = ks * 32 + lg * 8;
                const float* ap = obs + (size_t)arow * 256 + e0;
                float4 f0 = *(const float4*)ap;
                float4 f1 = *(const float4*)(ap + 4);
                short8 a;
                a[0] = f2bf(f0.x); a[1] = f2bf(f0.y); a[2] = f2bf(f0.z); a[3] = f2bf(f0.w);
                a[4] = f2bf(f1.x); a[5] = f2bf(f1.y); a[6] = f2bf(f1.z); a[7] = f2bf(f1.w);
                accq = __builtin_amdgcn_mfma_f32_16x16x32_bf16(a, *(const short8*)(wqp + e0), accq, 0, 0, 0);
                acck = __builtin_amdgcn_mfma_f32_16x16x32_bf16(a, *(const short8*)(wkp + e0), acck, 0, 0, 0);
                accv = __builtin_amdgcn_mfma_f32_16x16x32_bf16(a, *(const short8*)(wvp + e0), accv, 0, 0, 0);
            }
            const float scale = 0.35355339059327373f;  // 64^-0.25
            #pragma unroll
            for (int r = 0; r < 4; ++r) {
                int row = r0 + lg * 4 + r;
                qw[(size_t)row * 64 + w * 16 + lc] = f2bf(accq[r] * scale);
                kw[(size_t)row * 64 + w * 16 + lc] = f2bf(acck[r] * scale);
                ldsv[w * 16 + lc][lg * 4 + r] = f2bf(accv[r]);
            }
            __syncthreads();
            int b = r0 >> 11, s0 = r0 & 2047;
            int d = tid >> 2, sc = (tid & 3) * 4;
            short* dst = vt + (size_t)b * 64 * SQ + (size_t)d * SQ + s0 + sc;
            dst[0] = ldsv[d][sc]; dst[1] = ldsv[d][sc + 1];
            dst[2] = ldsv[d][sc + 2]; dst[3] = ldsv[d][sc + 3];
            __syncthreads();
        }
    }
    grid.sync();

    // ---------- P2: flash — p=exp(s) bf16 -> pbuf; PV partials + MFMA row-sums
    {
        short (*ldsP)[16][72] = (short(*)[16][72])smem;   // [4][16][72]
        for (int vb = bid; vb < 32 * NSP * NB; vb += gsz) {
            int qb = vb & 31, sp = (vb >> 5) & 7, b = vb >> 8;
            if (sp > qb) continue;
            int q0 = qb * 64;
            int r0 = q0 + w * 16;
            int eo = lg * 8;
            const short* qbase = qw + (size_t)b * SQ * 64;
            const short* kbase = kw + (size_t)b * SQ * 64;
            const short* vbase = vt + (size_t)b * 64 * SQ;
            short* pbase = pbuf + (size_t)b * SQ * SQ;
            short8 qf0 = *(const short8*)(qbase + (size_t)(r0 + lc) * 64 + eo);
            short8 qf1 = *(const short8*)(qbase + (size_t)(r0 + lc) * 64 + 32 + eo);
            f32x4 osum = {0.f, 0.f, 0.f, 0.f};
            f32x4 o[4];
            #pragma unroll
            for (int nj = 0; nj < 4; ++nj) o[nj] = (f32x4){0.f, 0.f, 0.f, 0.f};

            for (int kb = sp; kb <= qb; kb += NSP) {
                int k0 = kb * 64;
                f32x4 s[4];
                #pragma unroll
                for (int nj = 0; nj < 4; ++nj) s[nj] = (f32x4){0.f, 0.f, 0.f, 0.f};
                #pragma unroll
                for (int nj = 0; nj < 4; ++nj) {
                    short8 kf = *(const short8*)(kbase + (size_t)(k0 + nj * 16 + lc) * 64 + eo);
                    s[nj] = __builtin_amdgcn_mfma_f32_16x16x32_bf16(qf0, kf, s[nj], 0, 0, 0);
                }
                #pragma unroll
                for (int nj = 0; nj < 4; ++nj) {
                    short8 kf = *(const short8*)(kbase + (size_t)(k0 + nj * 16 + lc) * 64 + 32 + eo);
                    s[nj] = __builtin_amdgcn_mfma_f32_16x16x32_bf16(qf1, kf, s[nj], 0, 0, 0);
                }
                if (kb == qb) {
                    #pragma unroll
                    for (int nj = 0; nj < 4; ++nj)
                        #pragma unroll
                        for (int r = 0; r < 4; ++r)
                            if (k0 + nj * 16 + lc > r0 + lg * 4 + r) s[nj][r] = -INFINITY;
                }
                #pragma unroll
                for (int r = 0; r < 4; ++r)
                    #pragma unroll
                    for (int nj = 0; nj < 4; ++nj)
                        ldsP[w][lg * 4 + r][nj * 16 + lc] = f2bf(__expf(s[nj][r]));
                #pragma unroll
                for (int ks = 0; ks < 2; ++ks) {
                    short8 pa = *(const short8*)&ldsP[w][lc][ks * 32 + lg * 8];
                    *(short8*)(pbase + (size_t)(r0 + lc) * SQ + k0 + ks * 32 + lg * 8) = pa;
                    osum = __builtin_amdgcn_mfma_f32_16x16x32_bf16(pa, ones, osum, 0, 0, 0);
                    #pragma unroll
                    for (int nj = 0; nj < 4; ++nj) {
                        short8 vf = *(const short8*)(vbase + (size_t)(nj * 16 + lc) * SQ + k0 + ks * 32 + eo);
                        o[nj] = __builtin_amdgcn_mfma_f32_16x16x32_bf16(pa, vf, o[nj], 0, 0, 0);
                    }
                }
            }
            size_t pb = ((size_t)sp * NB + b) * SQ;
            #pragma unroll
            for (int r = 0; r < 4; ++r) {
                int row = r0 + lg * 4 + r;
                if (lc == 0) lpart[pb + row] = osum[r];
                #pragma unroll
                for (int nj = 0; nj < 4; ++nj)
                    op[(pb + row) * 64 + nj * 16 + lc] = o[nj][r];
            }
        }
    }
    grid.sync();

    // ---------- P3: combine partials, linv, fused MLP -> x
    {
        float* w1l = (float*)smem;                       // [64][64]
        float (*aol)[64] = (float(*)[64])(smem + 16384); // [8][64]
        const float4* src = (const float4*)W1;
        float4* dst = (float4*)w1l;
        #pragma unroll
        for (int i = 0; i < 4; ++i) dst[tid + i * 256] = src[tid + i * 256];
        __syncthreads();
        for (int vb = bid; vb < 2048; vb += gsz) {
            int row0 = vb * 8;
            #pragma unroll
            for (int rr = 0; rr < 2; ++rr) {
                int grow = row0 + w * 2 + rr;
                int b = grow >> 11, s = grow & 2047;
                int nsp = (s >> 6) + 1; if (nsp > NSP) nsp = NSP;
                float od = 0.f, lt = 0.f;
                for (int sp = 0; sp < nsp; ++sp) {
                    size_t base = (size_t)(sp * NB + b) * SQ + s;
                    od += op[base * 64 + l];
                    lt += lpart[base];
                }
                float inv = 1.f / lt;
                aol[w * 2 + rr][l] = od * inv;   // wave-local write/read
                if (l == 0) linv[grow] = inv;
            }
            #pragma unroll
            for (int rr = 0; rr < 2; ++rr) {
                int grow = row0 + w * 2 + rr;
                float t = b1[l];
                #pragma unroll 16
                for (int d = 0; d < 64; ++d) t += aol[w * 2 + rr][d] * w1l[d * 64 + l];
                float h = fmaxf(t, 0.f);
                float px = h * W2[l];
                px += __shfl_xor(px, 1);
                px += __shfl_xor(px, 2);
                px += __shfl_xor(px, 4);
                px += __shfl_xor(px, 8);
                px += __shfl_xor(px, 16);
                px += __shfl_xor(px, 32);
                if (l == 0) x[grow] = px + b2[0];
            }
        }
    }
    grid.sync();

    // ---------- P4: streaming finalize — attn = bf16(pbuf)*linv + zero-fill
    {
        float* liv = (float*)smem;   // [64]
        for (int vb = bid; vb < 2048; vb += gsz) {
            int csp = vb & 7, qb = (vb >> 3) & 31, b = vb >> 8;
            __syncthreads();
            if (tid < 64) liv[tid] = linv[(size_t)b * SQ + qb * 64 + tid];
            __syncthreads();
            float* abase = attn + (size_t)b * SQ * SQ;
            int colb = csp * 256 + l * 4;
            if ((colb >> 6) > qb) {
                float4 z = {0.f, 0.f, 0.f, 0.f};
                #pragma unroll
                for (int r = 0; r < 16; ++r) {
                    int row = qb * 64 + w * 16 + r;
                    *(float4*)(abase + (size_t)row * SQ + colb) = z;
                }
            } else {
                const short* pbase = pbuf + (size_t)b * SQ * SQ;
                #pragma unroll
                for (int r = 0; r < 16; ++r) {
                    int row = qb * 64 + w * 16 + r;
                    float inv = liv[w * 16 + r];
                    short4 pv = *(const short4*)(pbase + (size_t)row * SQ + colb);
                    float4 o;
                    o.x = bf2f(pv.x) * inv;
                    o.y = bf2f(pv.y) * inv;
                    o.z = bf2f(pv.z) * inv;
                    o.w = bf2f(pv.w) * inv;
                    *(float4*)(abase + (size_t)row * SQ + colb) = o;
                }
            }
        }
    }
}

// ================= fallback pipeline (R7 structure, flash updated) ==========
__global__ __launch_bounds__(256) void k_wt(const float* __restrict__ Wq,
                                            const float* __restrict__ Wk,
                                            const float* __restrict__ Wv,
                                            short* __restrict__ wt) {
    int o = blockIdx.x * 256 + threadIdx.x;
    int row = o >> 8, e = o & 255;
    int w = row >> 6, d = row & 63;
    const float* W = (w == 0) ? Wq : ((w == 1) ? Wk : Wv);
    wt[o] = f2bf(W[e * 64 + d]);
}

__global__ __launch_bounds__(256, 4) void k_proj(const float* __restrict__ obs,
                                                 const short* __restrict__ wt,
                                                 short* __restrict__ qw,
                                                 short* __restrict__ kw,
                                                 short* __restrict__ vt) {
    int tid = threadIdx.x, w = tid >> 6, l = tid & 63, lg = l >> 4, lc = l & 15;
    int r0 = blockIdx.x * 16;
    int arow = r0 + lc;
    f32x4 accq = {0.f,0.f,0.f,0.f}, acck = {0.f,0.f,0.f,0.f}, accv = {0.f,0.f,0.f,0.f};
    const short* wq = wt + (size_t)(w * 16 + lc) * 256;
    const short* wk = wt + (size_t)(64 + w * 16 + lc) * 256;
    const short* wv = wt + (size_t)(128 + w * 16 + lc) * 256;
    #pragma unroll
    for (int ks = 0; ks < 8; ++ks) {
        int e0 = ks * 32 + lg * 8;
        const float* ap = obs + (size_t)arow * 256 + e0;
        float4 f0 = *(const float4*)ap;
        float4 f1 = *(const float4*)(ap + 4);
        short8 a;
        a[0] = f2bf(f0.x); a[1] = f2bf(f0.y); a[2] = f2bf(f0.z); a[3] = f2bf(f0.w);
        a[4] = f2bf(f1.x); a[5] = f2bf(f1.y); a[6] = f2bf(f1.z); a[7] = f2bf(f1.w);
        accq = __builtin_amdgcn_mfma_f32_16x16x32_bf16(a, *(const short8*)(wq + e0), accq, 0, 0, 0);
        acck = __builtin_amdgcn_mfma_f32_16x16x32_bf16(a, *(const short8*)(wk + e0), acck, 0, 0, 0);
        accv = __builtin_amdgcn_mfma_f32_16x16x32_bf16(a, *(const short8*)(wv + e0), accv, 0, 0, 0);
    }
    const float scale = 0.35355339059327373f;
    __shared__ short ldsv[64][18];
    #pragma unroll
    for (int r = 0; r < 4; ++r) {
        int row = r0 + lg * 4 + r;
        qw[(size_t)row * 64 + w * 16 + lc] = f2bf(accq[r] * scale);
        kw[(size_t)row * 64 + w * 16 + lc] = f2bf(acck[r] * scale);
        ldsv[w * 16 + lc][lg * 4 + r] = f2bf(accv[r]);
    }
    __syncthreads();
    int b = r0 >> 11, s0 = r0 & 2047;
    int d = tid >> 2, sc = (tid & 3) * 4;
    short* dst = vt + (size_t)b * 64 * SQ + (size_t)d * SQ + s0 + sc;
    dst[0] = ldsv[d][sc]; dst[1] = ldsv[d][sc + 1];
    dst[2] = ldsv[d][sc + 2]; dst[3] = ldsv[d][sc + 3];
}

__global__ __launch_bounds__(256) void k_flash(const short* __restrict__ qw,
                                               const short* __restrict__ kw,
                                               const short* __restrict__ vt,
                                               float* __restrict__ op,
                                               float* __restrict__ lpart,
                                               short* __restrict__ pbuf) {
    int qb = blockIdx.x, sp = blockIdx.y, b = blockIdx.z;
    if (sp > qb) return;
    int q0 = qb * 64;
    int tid = threadIdx.x, w = tid >> 6, l = tid & 63, lg = l >> 4, lc = l & 15;
    int r0 = q0 + w * 16;
    int eo = lg * 8;
    __shared__ short ldsP[4][16][72];
    const short* qbase = qw + (size_t)b * SQ * 64;
    const short* kbase = kw + (size_t)b * SQ * 64;
    const short* vbase = vt + (size_t)b * 64 * SQ;
    short* pbase = pbuf + (size_t)b * SQ * SQ;
    short8 qf0 = *(const short8*)(qbase + (size_t)(r0 + lc) * 64 + eo);
    short8 qf1 = *(const short8*)(qbase + (size_t)(r0 + lc) * 64 + 32 + eo);
    short8 ones;
    #pragma unroll
    for (int i = 0; i < 8; ++i) ones[i] = (short)0x3F80;
    f32x4 osum = {0.f, 0.f, 0.f, 0.f};
    f32x4 o[4];
    #pragma unroll
    for (int nj = 0; nj < 4; ++nj) o[nj] = (f32x4){0.f, 0.f, 0.f, 0.f};

    for (int kb = sp; kb <= qb; kb += NSP) {
        int k0 = kb * 64;
        f32x4 s[4];
        #pragma unroll
        for (int nj = 0; nj < 4; ++nj) s[nj] = (f32x4){0.f, 0.f, 0.f, 0.f};
        #pragma unroll
        for (int nj = 0; nj < 4; ++nj) {
            short8 kf = *(const short8*)(kbase + (size_t)(k0 + nj * 16 + lc) * 64 + eo);
            s[nj] = __builtin_amdgcn_mfma_f32_16x16x32_bf16(qf0, kf, s[nj], 0, 0, 0);
        }
        #pragma unroll
        for (int nj = 0; nj < 4; ++nj) {
            short8 kf = *(const short8*)(kbase + (size_t)(k0 + nj * 16 + lc) * 64 + 32 + eo);
            s[nj] = __builtin_amdgcn_mfma_f32_16x16x32_bf16(qf1, kf, s[nj], 0, 0, 0);
        }
        if (kb == qb) {
            #pragma unroll
            for (int nj = 0; nj < 4; ++nj)
                #pragma unroll
                for (int r = 0; r < 4; ++r)
                    if (k0 + nj * 16 + lc > r0 + lg * 4 + r) s[nj][r] = -INFINITY;
        }
        #pragma unroll
        for (int r = 0; r < 4; ++r)
            #pragma unroll
            for (int nj = 0; nj < 4; ++nj)
                ldsP[w][lg * 4 + r][nj * 16 + lc] = f2bf(__expf(s[nj][r]));
        #pragma unroll
        for (int ks = 0; ks < 2; ++ks) {
            short8 pa = *(const short8*)&ldsP[w][lc][ks * 32 + lg * 8];
            *(short8*)(pbase + (size_t)(r0 + lc) * SQ + k0 + ks * 32 + lg * 8) = pa;
            osum = __builtin_amdgcn_mfma_f32_16x16x32_bf16(pa, ones, osum, 0, 0, 0);
            #pragma unroll
            for (int nj = 0; nj < 4; ++nj) {
                short8 vf = *(const short8*)(vbase + (size_t)(nj * 16 + lc) * SQ + k0 + ks * 32 + eo);
                o[nj] = __builtin_amdgcn_mfma_f32_16x16x32_bf16(pa, vf, o[nj], 0, 0, 0);
            }
        }
    }
    size_t pb = ((size_t)sp * NB + b) * SQ;
    #pragma unroll
    for (int r = 0; r < 4; ++r) {
        int row = r0 + lg * 4 + r;
        if (lc == 0) lpart[pb + row] = osum[r];
        #pragma unroll
        for (int nj = 0; nj < 4; ++nj)
            op[(pb + row) * 64 + nj * 16 + lc] = o[nj][r];
    }
}

__global__ __launch_bounds__(256) void k_combine(const float* __restrict__ op,
                                                 const float* __restrict__ lpart,
                                                 const float* __restrict__ W1,
                                                 const float* __restrict__ b1,
                                                 const float* __restrict__ W2,
                                                 const float* __restrict__ b2,
                                                 float* __restrict__ x,
                                                 float* __restrict__ linv) {
    int row0 = blockIdx.x * 8;
    int tid = threadIdx.x, w = tid >> 6, l = tid & 63;
    __shared__ float w1l[64][64];
    __shared__ float aol[8][64];
    {
        const float4* src = (const float4*)W1;
        float4* dst = (float4*)&w1l[0][0];
        #pragma unroll
        for (int i = 0; i < 4; ++i) dst[tid + i * 256] = src[tid + i * 256];
    }
    #pragma unroll
    for (int rr = 0; rr < 2; ++rr) {
        int grow = row0 + w * 2 + rr;
        int b = grow >> 11, s = grow & 2047;
        int nsp = (s >> 6) + 1; if (nsp > NSP) nsp = NSP;
        float od = 0.f, lt = 0.f;
        for (int sp = 0; sp < nsp; ++sp) {
            size_t base = (size_t)(sp * NB + b) * SQ + s;
            od += op[base * 64 + l];
            lt += lpart[base];
        }
        float inv = 1.f / lt;
        aol[w * 2 + rr][l] = od * inv;
        if (l == 0) linv[grow] = inv;
    }
    __syncthreads();
    #pragma unroll
    for (int rr = 0; rr < 2; ++rr) {
        int grow = row0 + w * 2 + rr;
        float t = b1[l];
        #pragma unroll 16
        for (int d = 0; d < 64; ++d) t += aol[w * 2 + rr][d] * w1l[d][l];
        float h = fmaxf(t, 0.f);
        float px = h * W2[l];
        px += __shfl_xor(px, 1);
        px += __shfl_xor(px, 2);
        px += __shfl_xor(px, 4);
        px += __shfl_xor(px, 8);
        px += __shfl_xor(px, 16);
        px += __shfl_xor(px, 32);
        if (l == 0) x[grow] = px + b2[0];
    }
}

__global__ __launch_bounds__(256) void k_write(const short* __restrict__ pbuf,
                                               const float* __restrict__ linv,
                                               float* __restrict__ attn) {
    int csp = blockIdx.x, qb = blockIdx.y, b = blockIdx.z;
    int tid = threadIdx.x, w = tid >> 6, l = tid & 63;
    __shared__ float liv[64];
    if (tid < 64) liv[tid] = linv[(size_t)b * SQ + qb * 64 + tid];
    __syncthreads();
    float* abase = attn + (size_t)b * SQ * SQ;
    int colb = csp * 256 + l * 4;
    if ((colb >> 6) > qb) {
        float4 z = {0.f, 0.f, 0.f, 0.f};
        #pragma unroll
        for (int r = 0; r < 16; ++r) {
            int row = qb * 64 + w * 16 + r;
            *(float4*)(abase + (size_t)row * SQ + colb) = z;
        }
        return;
    }
    const short* pbase = pbuf + (size_t)b * SQ * SQ;
    #pragma unroll
    for (int r = 0; r < 16; ++r) {
        int row = qb * 64 + w * 16 + r;
        float inv = liv[w * 16 + r];
        short4 pv = *(const short4*)(pbase + (size_t)row * SQ + colb);
        float4 o;
        o.x = bf2f(pv.x) * inv;
        o.y = bf2f(pv.y) * inv;
        o.z = bf2f(pv.z) * inv;
        o.w = bf2f(pv.w) * inv;
        *(float4*)(abase + (size_t)row * SQ + colb) = o;
    }
}

extern "C" void kernel_launch(void* const* d_in, const int* in_sizes, int n_in,
                              void* d_out, int out_size, void* d_ws, size_t ws_size,
                              hipStream_t stream) {
    const float* obs = (const float*)d_in[0];
    const float* Wq  = (const float*)d_in[2];
    const float* Wk  = (const float*)d_in[3];
    const float* Wv  = (const float*)d_in[4];
    const float* W1  = (const float*)d_in[5];
    const float* b1  = (const float*)d_in[6];
    const float* W2  = (const float*)d_in[7];
    const float* b2  = (const float*)d_in[8];

    float* x    = (float*)d_out;                    // [16384]
    float* attn = (float*)d_out + NB * SQ;          // [8][2048][2048]
    float* op   = attn;                             // PV partials alias attn region

    char* ws = (char*)d_ws;
    short* wt    = (short*)(ws);
    short* qw    = (short*)(ws + 131072);
    short* kw    = (short*)(ws + 2228224);
    short* vt    = (short*)(ws + 4325376);
    float* lpart = (float*)(ws + 6422528);
    float* linv  = (float*)(ws + 6946816);
    short* pbuf  = (short*)(ws + 7012352);          // 64 MiB

    int maxb = 0;
    hipError_t qrc = hipOccupancyMaxActiveBlocksPerMultiprocessor(&maxb, k_mega, 256, 0);
    if (qrc != hipSuccess || maxb < 1) maxb = 2;
    int grid = 256 * maxb;
    if (grid > 1024) grid = 1024;

    void* args[] = {&obs, &Wq, &Wk, &Wv, &W1, &b1, &W2, &b2, &x, &attn,
                    &wt, &qw, &kw, &vt, &lpart, &linv, &pbuf, &op};
    hipError_t rc = hipLaunchCooperativeKernel((void*)k_mega, dim3(grid), dim3(256),
                                               args, 0, stream);
    if (rc != hipSuccess && grid > 512) {
        grid = 512;
        rc = hipLaunchCooperativeKernel((void*)k_mega, dim3(grid), dim3(256),
                                        args, 0, stream);
    }
    if (rc != hipSuccess) {   // fallback: stream-ordered pipeline (identical math)
        k_wt<<<dim3(192), dim3(256), 0, stream>>>(Wq, Wk, Wv, wt);
        k_proj<<<dim3(1024), dim3(256), 0, stream>>>(obs, wt, qw, kw, vt);
        k_flash<<<dim3(32, NSP, NB), dim3(256), 0, stream>>>(qw, kw, vt, op, lpart, pbuf);
        k_combine<<<dim3(2048), dim3(256), 0, stream>>>(op, lpart, W1, b1, W2, b2, x, linv);
        k_write<<<dim3(8, 32, NB), dim3(256), 0, stream>>>(pbuf, linv, attn);
    }
}

// Round 10
// 142.971 us; speedup vs baseline: 2.4849x; 2.4849x over previous
//
#include <hip/hip_runtime.h>
#include <hip/hip_bf16.h>
#include <math.h>

#define NB 8
#define SQ 2048
#define NSP 8    // kv splits in flash pass

typedef __attribute__((ext_vector_type(8))) short short8;
typedef __attribute__((ext_vector_type(4))) float f32x4;

__device__ __forceinline__ short f2bf(float f) {
    union { float f; unsigned u; } v; v.f = f;
    unsigned r = v.u + 0x7FFF + ((v.u >> 16) & 1);  // RNE
    return (short)(r >> 16);
}
__device__ __forceinline__ short f2bf_trunc(float f) {
    union { float f; unsigned u; } v; v.f = f;
    return (short)(v.u >> 16);
}
__device__ __forceinline__ float bf2f(short s) {
    union { unsigned u; float f; } v; v.u = ((unsigned)(unsigned short)s) << 16;
    return v.f;
}

// ---------------- K0: build WT bf16 [192][256]  (rows 0-63 Wq, 64-127 Wk, 128-191 Wv)
__global__ __launch_bounds__(256) void k_wt(const float* __restrict__ Wq,
                                            const float* __restrict__ Wk,
                                            const float* __restrict__ Wv,
                                            short* __restrict__ wt) {
    int o = blockIdx.x * 256 + threadIdx.x;
    int row = o >> 8, e = o & 255;
    int w = row >> 6, d = row & 63;
    const float* W = (w == 0) ? Wq : ((w == 1) ? Wk : Wv);
    wt[o] = f2bf(W[e * 64 + d]);
}

// ---------------- K1: projection GEMM, 16 rows/block, waves split cols {q,k,v}
__global__ __launch_bounds__(256, 4) void k_proj(const float* __restrict__ obs,
                                                 const short* __restrict__ wt,
                                                 short* __restrict__ qw,
                                                 short* __restrict__ kw,
                                                 short* __restrict__ vt) {
    int tid = threadIdx.x, w = tid >> 6, l = tid & 63, lg = l >> 4, lc = l & 15;
    int r0 = blockIdx.x * 16;
    int arow = r0 + lc;
    f32x4 accq = {0.f,0.f,0.f,0.f}, acck = {0.f,0.f,0.f,0.f}, accv = {0.f,0.f,0.f,0.f};
    const short* wq = wt + (size_t)(w * 16 + lc) * 256;
    const short* wk = wt + (size_t)(64 + w * 16 + lc) * 256;
    const short* wv = wt + (size_t)(128 + w * 16 + lc) * 256;
    #pragma unroll
    for (int ks = 0; ks < 8; ++ks) {
        int e0 = ks * 32 + lg * 8;
        const float* ap = obs + (size_t)arow * 256 + e0;
        float4 f0 = *(const float4*)ap;
        float4 f1 = *(const float4*)(ap + 4);
        short8 a;
        a[0] = f2bf(f0.x); a[1] = f2bf(f0.y); a[2] = f2bf(f0.z); a[3] = f2bf(f0.w);
        a[4] = f2bf(f1.x); a[5] = f2bf(f1.y); a[6] = f2bf(f1.z); a[7] = f2bf(f1.w);
        accq = __builtin_amdgcn_mfma_f32_16x16x32_bf16(a, *(const short8*)(wq + e0), accq, 0, 0, 0);
        acck = __builtin_amdgcn_mfma_f32_16x16x32_bf16(a, *(const short8*)(wk + e0), acck, 0, 0, 0);
        accv = __builtin_amdgcn_mfma_f32_16x16x32_bf16(a, *(const short8*)(wv + e0), accv, 0, 0, 0);
    }
    const float scale = 0.35355339059327373f;
    __shared__ short ldsv[64][18];
    #pragma unroll
    for (int r = 0; r < 4; ++r) {
        int row = r0 + lg * 4 + r;
        qw[(size_t)row * 64 + w * 16 + lc] = f2bf(accq[r] * scale);
        kw[(size_t)row * 64 + w * 16 + lc] = f2bf(acck[r] * scale);
        ldsv[w * 16 + lc][lg * 4 + r] = f2bf(accv[r]);
    }
    __syncthreads();
    int b = r0 >> 11, s0 = r0 & 2047;
    int d = tid >> 2, sc = (tid & 3) * 4;
    short* dst = vt + (size_t)b * 64 * SQ + (size_t)d * SQ + s0 + sc;
    dst[0] = ldsv[d][sc]; dst[1] = ldsv[d][sc + 1];
    dst[2] = ldsv[d][sc + 2]; dst[3] = ldsv[d][sc + 3];
}

// ---------------- K2: flash — double-buffered LDS, ones-MFMA rowsum, trunc convert
__global__ __launch_bounds__(256) void k_flash(const short* __restrict__ qw,
                                               const short* __restrict__ kw,
                                               const short* __restrict__ vt,
                                               float* __restrict__ op,
                                               float* __restrict__ lpart,
                                               short* __restrict__ pbuf) {
    int qb = blockIdx.x, sp = blockIdx.y, b = blockIdx.z;
    if (sp > qb) return;
    int q0 = qb * 64;
    int tid = threadIdx.x, w = tid >> 6, l = tid & 63, lg = l >> 4, lc = l & 15;
    int r0 = q0 + w * 16;
    int eo = lg * 8;
    __shared__ short ldsP[2][4][16][72];   // double-buffered by tile parity
    const short* qbase = qw + (size_t)b * SQ * 64;
    const short* kbase = kw + (size_t)b * SQ * 64;
    const short* vbase = vt + (size_t)b * 64 * SQ;
    short* pbase = pbuf + (size_t)b * SQ * SQ;
    short8 qf0 = *(const short8*)(qbase + (size_t)(r0 + lc) * 64 + eo);
    short8 qf1 = *(const short8*)(qbase + (size_t)(r0 + lc) * 64 + 32 + eo);
    short8 ones;
    #pragma unroll
    for (int i = 0; i < 8; ++i) ones[i] = (short)0x3F80;   // bf16 1.0
    f32x4 osum = {0.f, 0.f, 0.f, 0.f};
    f32x4 o[4];
    #pragma unroll
    for (int nj = 0; nj < 4; ++nj) o[nj] = (f32x4){0.f, 0.f, 0.f, 0.f};

    int pty = 0;
    for (int kb = sp; kb <= qb; kb += NSP, pty ^= 1) {
        int k0 = kb * 64;
        f32x4 s[4];
        #pragma unroll
        for (int nj = 0; nj < 4; ++nj) s[nj] = (f32x4){0.f, 0.f, 0.f, 0.f};
        #pragma unroll
        for (int nj = 0; nj < 4; ++nj) {
            short8 kf = *(const short8*)(kbase + (size_t)(k0 + nj * 16 + lc) * 64 + eo);
            s[nj] = __builtin_amdgcn_mfma_f32_16x16x32_bf16(qf0, kf, s[nj], 0, 0, 0);
        }
        #pragma unroll
        for (int nj = 0; nj < 4; ++nj) {
            short8 kf = *(const short8*)(kbase + (size_t)(k0 + nj * 16 + lc) * 64 + 32 + eo);
            s[nj] = __builtin_amdgcn_mfma_f32_16x16x32_bf16(qf1, kf, s[nj], 0, 0, 0);
        }
        if (kb == qb) {
            #pragma unroll
            for (int nj = 0; nj < 4; ++nj)
                #pragma unroll
                for (int r = 0; r < 4; ++r)
                    if (k0 + nj * 16 + lc > r0 + lg * 4 + r) s[nj][r] = -INFINITY;
        }
        #pragma unroll
        for (int r = 0; r < 4; ++r)
            #pragma unroll
            for (int nj = 0; nj < 4; ++nj)
                ldsP[pty][w][lg * 4 + r][nj * 16 + lc] = f2bf_trunc(__expf(s[nj][r]));
        #pragma unroll
        for (int ks = 0; ks < 2; ++ks) {
            short8 pa = *(const short8*)&ldsP[pty][w][lc][ks * 32 + lg * 8];
            *(short8*)(pbase + (size_t)(r0 + lc) * SQ + k0 + ks * 32 + lg * 8) = pa;
            osum = __builtin_amdgcn_mfma_f32_16x16x32_bf16(pa, ones, osum, 0, 0, 0);
            #pragma unroll
            for (int nj = 0; nj < 4; ++nj) {
                short8 vf = *(const short8*)(vbase + (size_t)(nj * 16 + lc) * SQ + k0 + ks * 32 + eo);
                o[nj] = __builtin_amdgcn_mfma_f32_16x16x32_bf16(pa, vf, o[nj], 0, 0, 0);
            }
        }
    }
    size_t pb = ((size_t)sp * NB + b) * SQ;
    #pragma unroll
    for (int r = 0; r < 4; ++r) {
        int row = r0 + lg * 4 + r;
        if (lc == 0) lpart[pb + row] = osum[r];
        #pragma unroll
        for (int nj = 0; nj < 4; ++nj)
            op[(pb + row) * 64 + nj * 16 + lc] = o[nj][r];
    }
}

// ---------------- K3: combine PV+l partials, compute linv, fused MLP -> x
__global__ __launch_bounds__(256) void k_combine(const float* __restrict__ op,
                                                 const float* __restrict__ lpart,
                                                 const float* __restrict__ W1,
                                                 const float* __restrict__ b1,
                                                 const float* __restrict__ W2,
                                                 const float* __restrict__ b2,
                                                 float* __restrict__ x,
                                                 float* __restrict__ linv) {
    int row0 = blockIdx.x * 8;
    int tid = threadIdx.x, w = tid >> 6, l = tid & 63;
    __shared__ float w1l[64][64];
    __shared__ float aol[8][64];
    {
        const float4* src = (const float4*)W1;
        float4* dst = (float4*)&w1l[0][0];
        #pragma unroll
        for (int i = 0; i < 4; ++i) dst[tid + i * 256] = src[tid + i * 256];
    }
    #pragma unroll
    for (int rr = 0; rr < 2; ++rr) {
        int grow = row0 + w * 2 + rr;
        int b = grow >> 11, s = grow & 2047;
        int nsp = (s >> 6) + 1; if (nsp > NSP) nsp = NSP;
        float od = 0.f, lt = 0.f;
        for (int sp = 0; sp < nsp; ++sp) {
            size_t base = (size_t)(sp * NB + b) * SQ + s;
            od += op[base * 64 + l];
            lt += lpart[base];
        }
        float inv = 1.f / lt;
        aol[w * 2 + rr][l] = od * inv;
        if (l == 0) linv[grow] = inv;
    }
    __syncthreads();
    #pragma unroll
    for (int rr = 0; rr < 2; ++rr) {
        int grow = row0 + w * 2 + rr;
        float t = b1[l];
        #pragma unroll 16
        for (int d = 0; d < 64; ++d) t += aol[w * 2 + rr][d] * w1l[d][l];
        float h = fmaxf(t, 0.f);
        float px = h * W2[l];
        px += __shfl_xor(px, 1);
        px += __shfl_xor(px, 2);
        px += __shfl_xor(px, 4);
        px += __shfl_xor(px, 8);
        px += __shfl_xor(px, 16);
        px += __shfl_xor(px, 32);
        if (l == 0) x[grow] = px + b2[0];
    }
}

// ---------------- K4: streaming finalize — attn = bf16(pbuf)*linv + zero-fill
__global__ __launch_bounds__(256) void k_write(const short* __restrict__ pbuf,
                                               const float* __restrict__ linv,
                                               float* __restrict__ attn) {
    int csp = blockIdx.x, qb = blockIdx.y, b = blockIdx.z;
    int tid = threadIdx.x, w = tid >> 6, l = tid & 63;
    __shared__ float liv[64];
    if (tid < 64) liv[tid] = linv[(size_t)b * SQ + qb * 64 + tid];
    __syncthreads();
    float* abase = attn + (size_t)b * SQ * SQ;
    int colb = csp * 256 + l * 4;
    if ((colb >> 6) > qb) {
        float4 z = {0.f, 0.f, 0.f, 0.f};
        #pragma unroll
        for (int r = 0; r < 16; ++r) {
            int row = qb * 64 + w * 16 + r;
            *(float4*)(abase + (size_t)row * SQ + colb) = z;
        }
        return;
    }
    const short* pbase = pbuf + (size_t)b * SQ * SQ;
    #pragma unroll
    for (int r = 0; r < 16; ++r) {
        int row = qb * 64 + w * 16 + r;
        float inv = liv[w * 16 + r];
        short4 pv = *(const short4*)(pbase + (size_t)row * SQ + colb);
        float4 o;
        o.x = bf2f(pv.x) * inv;
        o.y = bf2f(pv.y) * inv;
        o.z = bf2f(pv.z) * inv;
        o.w = bf2f(pv.w) * inv;
        *(float4*)(abase + (size_t)row * SQ + colb) = o;
    }
}

extern "C" void kernel_launch(void* const* d_in, const int* in_sizes, int n_in,
                              void* d_out, int out_size, void* d_ws, size_t ws_size,
                              hipStream_t stream) {
    const float* obs = (const float*)d_in[0];
    const float* Wq  = (const float*)d_in[2];
    const float* Wk  = (const float*)d_in[3];
    const float* Wv  = (const float*)d_in[4];
    const float* W1  = (const float*)d_in[5];
    const float* b1  = (const float*)d_in[6];
    const float* W2  = (const float*)d_in[7];
    const float* b2  = (const float*)d_in[8];

    float* x    = (float*)d_out;                    // [16384]
    float* attn = (float*)d_out + NB * SQ;          // [8][2048][2048]
    float* op   = attn;                             // PV partials alias attn region

    char* ws = (char*)d_ws;
    short* wt    = (short*)(ws);
    short* qw    = (short*)(ws + 131072);
    short* kw    = (short*)(ws + 2228224);
    short* vt    = (short*)(ws + 4325376);
    float* lpart = (float*)(ws + 6422528);
    float* linv  = (float*)(ws + 6946816);
    short* pbuf  = (short*)(ws + 7012352);          // 64 MiB

    k_wt<<<dim3(192), dim3(256), 0, stream>>>(Wq, Wk, Wv, wt);
    k_proj<<<dim3(1024), dim3(256), 0, stream>>>(obs, wt, qw, kw, vt);
    k_flash<<<dim3(32, NSP, NB), dim3(256), 0, stream>>>(qw, kw, vt, op, lpart, pbuf);
    k_combine<<<dim3(2048), dim3(256), 0, stream>>>(op, lpart, W1, b1, W2, b2, x, linv);
    k_write<<<dim3(8, 32, NB), dim3(256), 0, stream>>>(pbuf, linv, attn);
}